// Round 7
// baseline (481.070 us; speedup 1.0000x reference)
//
#include <hip/hip_runtime.h>
#include <stdint.h>

typedef short bf16x8 __attribute__((ext_vector_type(8)));
typedef unsigned short u16x8 __attribute__((ext_vector_type(8)));
typedef float f32x4 __attribute__((ext_vector_type(4)));

#define NPB 512          // nodes per bucket
#define BSHIFT 9
#define MAXBUCK 256      // supports N <= 131072
#define STAGE_CAP 12288  // per-bucket csr staging (mean 8163, sigma ~90)
#define LROW 136         // LDS mean row stride in shorts (272 B)

__device__ __forceinline__ short f2bf(float f) {
    uint32_t u = __float_as_uint(f);
    u += 0x7fffu + ((u >> 16) & 1u);   // round-to-nearest-even
    return (short)(u >> 16);
}
__device__ __forceinline__ float bf2f(unsigned short s) {
    return __uint_as_float((uint32_t)s << 16);
}

// ---- x f32 -> bf16, 8 elems/thread ----
__global__ __launch_bounds__(256) void convx_kernel(const float* __restrict__ in,
                                                    short* __restrict__ out, int n) {
    int i = (blockIdx.x * 256 + threadIdx.x) * 8;
    if (i + 8 <= n) {
        const float4 v0 = *(const float4*)(in + i);
        const float4 v1 = *(const float4*)(in + i + 4);
        bf16x8 o;
        o[0] = f2bf(v0.x); o[1] = f2bf(v0.y); o[2] = f2bf(v0.z); o[3] = f2bf(v0.w);
        o[4] = f2bf(v1.x); o[5] = f2bf(v1.y); o[6] = f2bf(v1.z); o[7] = f2bf(v1.w);
        *(bf16x8*)(out + i) = o;
    } else {
        for (int j = i; j < n; ++j) out[j] = f2bf(in[j]);
    }
}

// ---- all 4 weight matrices f32 -> bf16 in one launch ----
__global__ void convw4_kernel(const float* __restrict__ w0, const float* __restrict__ w1,
                              const float* __restrict__ w2, const float* __restrict__ w3,
                              short* __restrict__ o0, short* __restrict__ o1,
                              short* __restrict__ o2, short* __restrict__ o3) {
    int i = blockIdx.x * 256 + threadIdx.x;
    o0[i] = f2bf(w0[i]);
    o1[i] = f2bf(w1[i]);
    o2[i] = f2bf(w2[i]);
    o3[i] = f2bf(w3[i]);
}

// ---- coarse bucket histogram (LDS-aggregated) ----
__global__ __launch_bounds__(256) void bhist_kernel(const int* __restrict__ dst,
                                                    int* __restrict__ bcnt, int E, int B) {
    __shared__ int h[MAXBUCK];
    for (int i = threadIdx.x; i < B; i += 256) h[i] = 0;
    __syncthreads();
    int stride = gridDim.x * 256;
    for (int e = blockIdx.x * 256 + threadIdx.x; e < E; e += stride)
        atomicAdd(&h[dst[e] >> BSHIFT], 1);
    __syncthreads();
    for (int i = threadIdx.x; i < B; i += 256)
        if (h[i]) atomicAdd(&bcnt[i], h[i]);
}

// ---- scan bucket counts -> bases + init cursors; rowptr[N]=E ----
__global__ __launch_bounds__(256) void bscan_kernel(const int* __restrict__ bcnt,
                                                    int* __restrict__ bbase,
                                                    int* __restrict__ gcur,
                                                    int* __restrict__ rowptr,
                                                    int E, int N, int B) {
    __shared__ int s[256];
    int t = threadIdx.x;
    int v = (t < B) ? bcnt[t] : 0;
    s[t] = v;
    __syncthreads();
    for (int off = 1; off < 256; off <<= 1) {
        int a = (t >= off) ? s[t - off] : 0;
        __syncthreads();
        s[t] += a;
        __syncthreads();
    }
    int excl = s[t] - v;
    if (t < B) { bbase[t] = excl; gcur[t] = excl; }
    if (t == B - 1) bbase[B] = excl + v;
    if (t == 0) rowptr[N] = E;
}

// ---- bin edges into bucket regions as packed records (src<<9 | dst&511) ----
// constant-indexed register arrays (no dynamic indexing -> no scratch spill)
__global__ __launch_bounds__(256) void bin_kernel(const int* __restrict__ src,
                                                  const int* __restrict__ dst,
                                                  int* __restrict__ gcur,
                                                  unsigned int* __restrict__ binned,
                                                  int E, int B) {
    __shared__ int cnt[MAXBUCK];
    __shared__ int base[MAXBUCK];
    for (int i = threadIdx.x; i < B; i += 256) cnt[i] = 0;
    __syncthreads();
    const int e0 = blockIdx.x * 4096;
    int myS[16], myD[16];
#pragma unroll
    for (int i = 0; i < 16; ++i) {
        int e = e0 + threadIdx.x + i * 256;
        bool v = e < E;
        myS[i] = v ? src[e] : 0;
        myD[i] = v ? dst[e] : -1;
    }
#pragma unroll
    for (int i = 0; i < 16; ++i)
        if (myD[i] >= 0) atomicAdd(&cnt[myD[i] >> BSHIFT], 1);
    __syncthreads();
    for (int i = threadIdx.x; i < B; i += 256) {
        int c = cnt[i];
        base[i] = c ? atomicAdd(&gcur[i], c) : 0;
        cnt[i] = 0;   // reuse as local cursor
    }
    __syncthreads();
#pragma unroll
    for (int i = 0; i < 16; ++i) {
        if (myD[i] >= 0) {
            int b = myD[i] >> BSHIFT;
            int off = atomicAdd(&cnt[b], 1);
            binned[base[b] + off] = ((unsigned)myS[i] << BSHIFT) | (unsigned)(myD[i] & (NPB - 1));
        }
    }
}

// ---- per-bucket: local hist + scan -> rowptr; LDS scatter -> coalesced csr ----
__global__ __launch_bounds__(256) void build_kernel(const unsigned int* __restrict__ binned,
                                                    const int* __restrict__ bbase,
                                                    int* __restrict__ rowptr,
                                                    int* __restrict__ csr, int N) {
    __shared__ int hist[NPB];
    __shared__ int cur[NPB];
    __shared__ int scanb[256];
    __shared__ int stage[STAGE_CAP];
    const int b = blockIdx.x;
    const int t = threadIdx.x;
    const int cbeg = bbase[b], cend = bbase[b + 1];
    const int cnt = cend - cbeg;
    for (int i = t; i < NPB; i += 256) hist[i] = 0;
    __syncthreads();
    for (int i = t; i < cnt; i += 256)
        atomicAdd(&hist[binned[cbeg + i] & (NPB - 1)], 1);
    __syncthreads();
    const int h0 = hist[2 * t], h1 = hist[2 * t + 1];
    const int ps = h0 + h1;
    scanb[t] = ps;
    __syncthreads();
    for (int off = 1; off < 256; off <<= 1) {
        int a = (t >= off) ? scanb[t - off] : 0;
        __syncthreads();
        scanb[t] += a;
        __syncthreads();
    }
    const int e0 = scanb[t] - ps;
    cur[2 * t]     = e0;
    cur[2 * t + 1] = e0 + h0;
    __syncthreads();
    const int node0 = b << BSHIFT;
    for (int i = t; i < NPB; i += 256) {
        int node = node0 + i;
        if (node < N) rowptr[node] = cbeg + cur[i];
    }
    __syncthreads();
    for (int i = t; i < cnt; i += 256) {
        unsigned rec = binned[cbeg + i];
        int ld  = rec & (NPB - 1);
        int pos = atomicAdd(&cur[ld], 1);
        if (pos < STAGE_CAP) stage[pos] = (int)(rec >> BSHIFT);
        else                 csr[cbeg + pos] = (int)(rec >> BSHIFT);
    }
    __syncthreads();
    const int lim = cnt < STAGE_CAP ? cnt : STAGE_CAP;
    for (int i = t; i < lim; i += 256)
        csr[cbeg + i] = stage[i];
}

// ---- fused layer: out = [relu]( mean(feat) @ Wl^T + b + feat @ Wr^T ) ----
// Block = 4 waves = 64 nodes. Phase 1: WHOLE WAVE per node — one VMEM instr
// loads the node's full edge list (csr[beg+lane], deg<=64), indices broadcast
// in-register via __shfl; quarter q handles edge it*4+q, lane ql covers 16 B
// of the 256 B row. Wave-uniform loop bounds -> no divergence; all feat loads
// of a node issue back-to-back. Cross-quarter shfl_xor reduce, mean -> LDS.
// Phase 2: MFMA 16x128 tile, A(mean) from own LDS rows (no barrier needed).
template <bool RELU>
__global__ __launch_bounds__(256) void fused_kernel(
    const short* __restrict__ feat, const int* __restrict__ csr,
    const int* __restrict__ rowptr,
    const short* __restrict__ Wl, const short* __restrict__ Wr,
    const float* __restrict__ bias,
    short* __restrict__ outb, float* __restrict__ outf, int N)
{
    __shared__ short lmean[64 * LROW];
    const int lane = threadIdx.x & 63;
    const int wave = threadIdx.x >> 6;
    const int q    = lane >> 4;          // quarter
    const int ql   = lane & 15;          // lane in quarter
    const int m0   = blockIdx.x * 64 + wave * 16;

    // ---- phase 1: wave processes its 16 nodes sequentially
    for (int n = 0; n < 16; ++n) {
        const int node = m0 + n;
        if (node >= N) break;
        const int beg = rowptr[node], end = rowptr[node + 1];
        float a0=0,a1=0,a2=0,a3=0,a4=0,a5=0,a6=0,a7=0;
        int base = beg;
        while (base < end) {
            const int cnt = min(end - base, 64);
            const int idx = (lane < cnt) ? csr[base + lane] : 0;
            for (int it = 0; it * 4 < cnt; ++it) {
                const int sel = it * 4 + q;
                const int s = __shfl(idx, sel);
                if (sel < cnt) {
                    u16x8 u = *(const u16x8*)(feat + (size_t)s * 128 + ql * 8);
                    a0 += bf2f(u[0]); a1 += bf2f(u[1]);
                    a2 += bf2f(u[2]); a3 += bf2f(u[3]);
                    a4 += bf2f(u[4]); a5 += bf2f(u[5]);
                    a6 += bf2f(u[6]); a7 += bf2f(u[7]);
                }
            }
            base += 64;
        }
        // reduce across the 4 quarters (xor 16, then 32)
        a0 += __shfl_xor(a0, 16); a1 += __shfl_xor(a1, 16);
        a2 += __shfl_xor(a2, 16); a3 += __shfl_xor(a3, 16);
        a4 += __shfl_xor(a4, 16); a5 += __shfl_xor(a5, 16);
        a6 += __shfl_xor(a6, 16); a7 += __shfl_xor(a7, 16);
        a0 += __shfl_xor(a0, 32); a1 += __shfl_xor(a1, 32);
        a2 += __shfl_xor(a2, 32); a3 += __shfl_xor(a3, 32);
        a4 += __shfl_xor(a4, 32); a5 += __shfl_xor(a5, 32);
        a6 += __shfl_xor(a6, 32); a7 += __shfl_xor(a7, 32);
        if (q == 0) {
            const float r = 1.0f / fmaxf((float)(end - beg), 1.0f);
            bf16x8 o;
            o[0] = f2bf(a0 * r); o[1] = f2bf(a1 * r);
            o[2] = f2bf(a2 * r); o[3] = f2bf(a3 * r);
            o[4] = f2bf(a4 * r); o[5] = f2bf(a5 * r);
            o[6] = f2bf(a6 * r); o[7] = f2bf(a7 * r);
            *(bf16x8*)(lmean + (size_t)(wave * 16 + n) * LROW + ql * 8) = o;
        }
    }
    // no __syncthreads: each wave reads only the 16 LDS rows it wrote

    // ---- phase 2: 16x128 MFMA tile
    f32x4 acc[8];
#pragma unroll
    for (int i = 0; i < 8; ++i) acc[i] = (f32x4)0.0f;
    const bool valid = (m0 + ql < N);

#pragma unroll
    for (int kk = 0; kk < 4; ++kk) {
        const int kb = kk * 32 + q * 8;
        const bf16x8 a = *(const bf16x8*)(lmean + (size_t)(wave * 16 + ql) * LROW + kb);
#pragma unroll
        for (int nt = 0; nt < 8; ++nt) {
            const bf16x8 b = *(const bf16x8*)(Wl + (size_t)(nt * 16 + ql) * 128 + kb);
            acc[nt] = __builtin_amdgcn_mfma_f32_16x16x32_bf16(a, b, acc[nt], 0, 0, 0);
        }
    }
#pragma unroll
    for (int kk = 0; kk < 4; ++kk) {
        const int kb = kk * 32 + q * 8;
        bf16x8 a = (bf16x8)0;
        if (valid) a = *(const bf16x8*)(feat + (size_t)(m0 + ql) * 128 + kb);
#pragma unroll
        for (int nt = 0; nt < 8; ++nt) {
            const bf16x8 b = *(const bf16x8*)(Wr + (size_t)(nt * 16 + ql) * 128 + kb);
            acc[nt] = __builtin_amdgcn_mfma_f32_16x16x32_bf16(a, b, acc[nt], 0, 0, 0);
        }
    }

    const int rbase = m0 + q * 4;
#pragma unroll
    for (int nt = 0; nt < 8; ++nt) {
        const int col = nt * 16 + ql;
        const float bc = bias[col];
#pragma unroll
        for (int r = 0; r < 4; ++r) {
            const int node = rbase + r;
            if (node < N) {
                float v = acc[nt][r] + bc;
                if (RELU) outb[(size_t)node * 128 + col] = f2bf(fmaxf(v, 0.0f));
                else      outf[(size_t)node * 128 + col] = v;
            }
        }
    }
}

extern "C" void kernel_launch(void* const* d_in, const int* in_sizes, int n_in,
                              void* d_out, int out_size, void* d_ws, size_t ws_size,
                              hipStream_t stream) {
    const float* x   = (const float*)d_in[0];
    const int*   ei  = (const int*)d_in[1];
    const float* Wl1 = (const float*)d_in[2];
    const float* bl1 = (const float*)d_in[3];
    const float* Wr1 = (const float*)d_in[4];
    const float* Wl2 = (const float*)d_in[5];
    const float* bl2 = (const float*)d_in[6];
    const float* Wr2 = (const float*)d_in[7];

    const int N = in_sizes[0] / 128;
    const int E = in_sizes[1] / 2;
    const int* src = ei;
    const int* dst = ei + E;
    const int B = (N + NPB - 1) >> BSHIFT;   // 196 for N=100000

    // ws: h_bf16 | 4x bf16 weights | rowptr | csr | binned | bucket meta (~39 MB)
    char* wsb = (char*)d_ws;
    short* hbuf = (short*)wsb;                                  // N*128 bf16
    size_t off = (size_t)N * 128 * 2;
    short* wl1 = (short*)(wsb + off); off += 16384 * 2;
    short* wr1 = (short*)(wsb + off); off += 16384 * 2;
    short* wl2 = (short*)(wsb + off); off += 16384 * 2;
    short* wr2 = (short*)(wsb + off); off += 16384 * 2;
    int* rowptr = (int*)(wsb + off);                            // N+1
    off += ((size_t)(N + 1) * 4 + 15) & ~(size_t)15;
    int* csr = (int*)(wsb + off);                               // E
    off += ((size_t)E * 4 + 15) & ~(size_t)15;
    unsigned int* binned = (unsigned int*)(wsb + off);          // E
    off += ((size_t)E * 4 + 15) & ~(size_t)15;
    int* bcnt  = (int*)(wsb + off);                             // MAXBUCK+1
    int* bbase = bcnt + (MAXBUCK + 1);                          // MAXBUCK+1
    int* gcur  = bbase + (MAXBUCK + 1);                         // MAXBUCK

    // d_out: xb (bf16 x) at base — read only by fused1, overwritten by fused2's out
    short* xb  = (short*)d_out;
    float* out = (float*)d_out;

    const int fusedBlocks = (N + 63) / 64;
    const int binBlocks   = (E + 4095) / 4096;

    convx_kernel<<<(N * 128 / 8 + 255) / 256, 256, 0, stream>>>(x, xb, N * 128);
    convw4_kernel<<<64, 256, 0, stream>>>(Wl1, Wr1, Wl2, Wr2, wl1, wr1, wl2, wr2);

    // build CSR by destination (bucketed, coalesced)
    (void)hipMemsetAsync(bcnt, 0, (size_t)(MAXBUCK + 1) * sizeof(int), stream);
    bhist_kernel<<<256, 256, 0, stream>>>(dst, bcnt, E, B);
    bscan_kernel<<<1, 256, 0, stream>>>(bcnt, bbase, gcur, rowptr, E, N, B);
    bin_kernel<<<binBlocks, 256, 0, stream>>>(src, dst, gcur, binned, E, B);
    build_kernel<<<B, 256, 0, stream>>>(binned, bbase, rowptr, csr, N);

    // layer 1: feat = xb (d_out), out = hbuf (ws)
    fused_kernel<true><<<fusedBlocks, 256, 0, stream>>>(xb, csr, rowptr, wl1, wr1, bl1,
                                                        hbuf, (float*)nullptr, N);
    // layer 2: feat = hbuf (ws), out = d_out (overwrites xb region; safe)
    fused_kernel<false><<<fusedBlocks, 256, 0, stream>>>(hbuf, csr, rowptr, wl2, wr2, bl2,
                                                         (short*)nullptr, out, N);
}

// Round 8
// 433.607 us; speedup vs baseline: 1.1095x; 1.1095x over previous
//
#include <hip/hip_runtime.h>
#include <stdint.h>

typedef short bf16x8 __attribute__((ext_vector_type(8)));
typedef float f32x4 __attribute__((ext_vector_type(4)));

#define NPB 512          // nodes per bucket
#define BSHIFT 9
#define MAXBUCK 256      // supports N <= 131072
#define STAGE_CAP 12288  // per-bucket csr staging (mean 8163, sigma ~90)

__device__ __forceinline__ short f2bf(float f) {
    uint32_t u = __float_as_uint(f);
    u += 0x7fffu + ((u >> 16) & 1u);   // round-to-nearest-even
    return (short)(u >> 16);
}
__device__ __forceinline__ float bf2f(unsigned short s) {
    return __uint_as_float((uint32_t)s << 16);
}

// ---- x f32 -> bf16, 8 elems/thread ----
__global__ __launch_bounds__(256) void convx_kernel(const float* __restrict__ in,
                                                    short* __restrict__ out, int n) {
    int i = (blockIdx.x * 256 + threadIdx.x) * 8;
    if (i + 8 <= n) {
        const float4 v0 = *(const float4*)(in + i);
        const float4 v1 = *(const float4*)(in + i + 4);
        bf16x8 o;
        o[0] = f2bf(v0.x); o[1] = f2bf(v0.y); o[2] = f2bf(v0.z); o[3] = f2bf(v0.w);
        o[4] = f2bf(v1.x); o[5] = f2bf(v1.y); o[6] = f2bf(v1.z); o[7] = f2bf(v1.w);
        *(bf16x8*)(out + i) = o;
    } else {
        for (int j = i; j < n; ++j) out[j] = f2bf(in[j]);
    }
}

// ---- all 4 weight matrices f32 -> bf16 in one launch ----
__global__ void convw4_kernel(const float* __restrict__ w0, const float* __restrict__ w1,
                              const float* __restrict__ w2, const float* __restrict__ w3,
                              short* __restrict__ o0, short* __restrict__ o1,
                              short* __restrict__ o2, short* __restrict__ o3) {
    int i = blockIdx.x * 256 + threadIdx.x;
    o0[i] = f2bf(w0[i]);
    o1[i] = f2bf(w1[i]);
    o2[i] = f2bf(w2[i]);
    o3[i] = f2bf(w3[i]);
}

// ---- coarse bucket histogram (LDS-aggregated) ----
__global__ __launch_bounds__(256) void bhist_kernel(const int* __restrict__ dst,
                                                    int* __restrict__ bcnt, int E, int B) {
    __shared__ int h[MAXBUCK];
    for (int i = threadIdx.x; i < B; i += 256) h[i] = 0;
    __syncthreads();
    int stride = gridDim.x * 256;
    for (int e = blockIdx.x * 256 + threadIdx.x; e < E; e += stride)
        atomicAdd(&h[dst[e] >> BSHIFT], 1);
    __syncthreads();
    for (int i = threadIdx.x; i < B; i += 256)
        if (h[i]) atomicAdd(&bcnt[i], h[i]);
}

// ---- scan bucket counts -> bases + init cursors; rowptr[N]=E ----
__global__ __launch_bounds__(256) void bscan_kernel(const int* __restrict__ bcnt,
                                                    int* __restrict__ bbase,
                                                    int* __restrict__ gcur,
                                                    int* __restrict__ rowptr,
                                                    int E, int N, int B) {
    __shared__ int s[256];
    int t = threadIdx.x;
    int v = (t < B) ? bcnt[t] : 0;
    s[t] = v;
    __syncthreads();
    for (int off = 1; off < 256; off <<= 1) {
        int a = (t >= off) ? s[t - off] : 0;
        __syncthreads();
        s[t] += a;
        __syncthreads();
    }
    int excl = s[t] - v;
    if (t < B) { bbase[t] = excl; gcur[t] = excl; }
    if (t == B - 1) bbase[B] = excl + v;
    if (t == 0) rowptr[N] = E;
}

// ---- bin edges into bucket regions as packed records (src<<9 | dst&511) ----
__global__ __launch_bounds__(256) void bin_kernel(const int* __restrict__ src,
                                                  const int* __restrict__ dst,
                                                  int* __restrict__ gcur,
                                                  unsigned int* __restrict__ binned,
                                                  int E, int B) {
    __shared__ int cnt[MAXBUCK];
    __shared__ int base[MAXBUCK];
    for (int i = threadIdx.x; i < B; i += 256) cnt[i] = 0;
    __syncthreads();
    const int e0 = blockIdx.x * 4096;
    int myS[16], myD[16];
#pragma unroll
    for (int i = 0; i < 16; ++i) {
        int e = e0 + threadIdx.x + i * 256;
        bool v = e < E;
        myS[i] = v ? src[e] : 0;
        myD[i] = v ? dst[e] : -1;
    }
#pragma unroll
    for (int i = 0; i < 16; ++i)
        if (myD[i] >= 0) atomicAdd(&cnt[myD[i] >> BSHIFT], 1);
    __syncthreads();
    for (int i = threadIdx.x; i < B; i += 256) {
        int c = cnt[i];
        base[i] = c ? atomicAdd(&gcur[i], c) : 0;
        cnt[i] = 0;   // reuse as local cursor
    }
    __syncthreads();
#pragma unroll
    for (int i = 0; i < 16; ++i) {
        if (myD[i] >= 0) {
            int b = myD[i] >> BSHIFT;
            int off = atomicAdd(&cnt[b], 1);
            binned[base[b] + off] = ((unsigned)myS[i] << BSHIFT) | (unsigned)(myD[i] & (NPB - 1));
        }
    }
}

// ---- per-bucket: local hist + scan -> rowptr; LDS scatter -> coalesced csr ----
__global__ __launch_bounds__(256) void build_kernel(const unsigned int* __restrict__ binned,
                                                    const int* __restrict__ bbase,
                                                    int* __restrict__ rowptr,
                                                    int* __restrict__ csr, int N) {
    __shared__ int hist[NPB];
    __shared__ int cur[NPB];
    __shared__ int scanb[256];
    __shared__ int stage[STAGE_CAP];
    const int b = blockIdx.x;
    const int t = threadIdx.x;
    const int cbeg = bbase[b], cend = bbase[b + 1];
    const int cnt = cend - cbeg;
    for (int i = t; i < NPB; i += 256) hist[i] = 0;
    __syncthreads();
    for (int i = t; i < cnt; i += 256)
        atomicAdd(&hist[binned[cbeg + i] & (NPB - 1)], 1);
    __syncthreads();
    const int h0 = hist[2 * t], h1 = hist[2 * t + 1];
    const int ps = h0 + h1;
    scanb[t] = ps;
    __syncthreads();
    for (int off = 1; off < 256; off <<= 1) {
        int a = (t >= off) ? scanb[t - off] : 0;
        __syncthreads();
        scanb[t] += a;
        __syncthreads();
    }
    const int e0 = scanb[t] - ps;
    cur[2 * t]     = e0;
    cur[2 * t + 1] = e0 + h0;
    __syncthreads();
    const int node0 = b << BSHIFT;
    for (int i = t; i < NPB; i += 256) {
        int node = node0 + i;
        if (node < N) rowptr[node] = cbeg + cur[i];
    }
    __syncthreads();
    for (int i = t; i < cnt; i += 256) {
        unsigned rec = binned[cbeg + i];
        int ld  = rec & (NPB - 1);
        int pos = atomicAdd(&cur[ld], 1);
        if (pos < STAGE_CAP) stage[pos] = (int)(rec >> BSHIFT);
        else                 csr[cbeg + pos] = (int)(rec >> BSHIFT);
    }
    __syncthreads();
    const int lim = cnt < STAGE_CAP ? cnt : STAGE_CAP;
    for (int i = t; i < lim; i += 256)
        csr[cbeg + i] = stage[i];
}

// ---- bf16 gather-mean: one wave per node, half-wave per edge row ----
// 8-edge unrolled body: 4 independent csr->feat load chains per lane in
// flight (covers L2-miss/LLC latency). Wave-uniform loop bounds -> no
// divergence. Lane owns 4 cols (ushort4 = 8 B/lane); cross-half shfl_xor(32).
__global__ __launch_bounds__(256) void agg_kernel(
    const short* __restrict__ feat, const int* __restrict__ csr,
    const int* __restrict__ rowptr, short* __restrict__ mean, int N) {
    int node = blockIdx.x * 4 + (threadIdx.x >> 6);
    if (node >= N) return;
    const int lane = threadIdx.x & 63;
    const int half = lane >> 5;
    const int c4   = (lane & 31) * 4;
    const int beg = rowptr[node], end = rowptr[node + 1];
    float a0 = 0.f, a1 = 0.f, a2 = 0.f, a3 = 0.f;
    int e = beg;
    for (; e + 8 <= end; e += 8) {
        const int s0 = csr[e + half];
        const int s1 = csr[e + 2 + half];
        const int s2 = csr[e + 4 + half];
        const int s3 = csr[e + 6 + half];
        ushort4 u0 = *(const ushort4*)(feat + (size_t)s0 * 128 + c4);
        ushort4 u1 = *(const ushort4*)(feat + (size_t)s1 * 128 + c4);
        ushort4 u2 = *(const ushort4*)(feat + (size_t)s2 * 128 + c4);
        ushort4 u3 = *(const ushort4*)(feat + (size_t)s3 * 128 + c4);
        a0 += bf2f(u0.x) + bf2f(u1.x) + bf2f(u2.x) + bf2f(u3.x);
        a1 += bf2f(u0.y) + bf2f(u1.y) + bf2f(u2.y) + bf2f(u3.y);
        a2 += bf2f(u0.z) + bf2f(u1.z) + bf2f(u2.z) + bf2f(u3.z);
        a3 += bf2f(u0.w) + bf2f(u1.w) + bf2f(u2.w) + bf2f(u3.w);
    }
    for (; e + 2 <= end; e += 2) {
        const int s = csr[e + half];
        ushort4 u = *(const ushort4*)(feat + (size_t)s * 128 + c4);
        a0 += bf2f(u.x); a1 += bf2f(u.y); a2 += bf2f(u.z); a3 += bf2f(u.w);
    }
    if (e < end && half == 0) {
        const int s = csr[e];
        ushort4 u = *(const ushort4*)(feat + (size_t)s * 128 + c4);
        a0 += bf2f(u.x); a1 += bf2f(u.y); a2 += bf2f(u.z); a3 += bf2f(u.w);
    }
    a0 += __shfl_xor(a0, 32);
    a1 += __shfl_xor(a1, 32);
    a2 += __shfl_xor(a2, 32);
    a3 += __shfl_xor(a3, 32);
    if (half == 0) {
        float r = 1.0f / fmaxf((float)(end - beg), 1.0f);
        ushort4 o;
        o.x = (unsigned short)f2bf(a0 * r);
        o.y = (unsigned short)f2bf(a1 * r);
        o.z = (unsigned short)f2bf(a2 * r);
        o.w = (unsigned short)f2bf(a3 * r);
        *(ushort4*)(mean + (size_t)node * 128 + c4) = o;
    }
}

// ---- fused SAGE linear: out = [relu]( mean @ Wl^T + b + xin @ Wr^T ) ----
// RELU=true: bf16 out (layer 1). RELU=false: f32 out (layer 2).
template <bool RELU>
__global__ __launch_bounds__(256) void gemm_kernel(
    const short* __restrict__ mean, const short* __restrict__ xin,
    const short* __restrict__ Wl, const short* __restrict__ Wr,
    const float* __restrict__ bias,
    short* __restrict__ outb, float* __restrict__ outf, int N)
{
    const int lane = threadIdx.x & 63;
    const int wave = threadIdx.x >> 6;
    const int m0   = blockIdx.x * 64 + wave * 16;
    const int mrow = m0 + (lane & 15);
    const int kq   = (lane >> 4) * 8;
    const bool valid = (mrow < N);

    f32x4 acc[8];
#pragma unroll
    for (int i = 0; i < 8; ++i) acc[i] = (f32x4)0.0f;

#pragma unroll
    for (int kk = 0; kk < 4; ++kk) {
        const int kb = kk * 32 + kq;
        bf16x8 a = (bf16x8)0;
        if (valid) a = *(const bf16x8*)(mean + (size_t)mrow * 128 + kb);
#pragma unroll
        for (int nt = 0; nt < 8; ++nt) {
            const bf16x8 b = *(const bf16x8*)(Wl + (size_t)(nt * 16 + (lane & 15)) * 128 + kb);
            acc[nt] = __builtin_amdgcn_mfma_f32_16x16x32_bf16(a, b, acc[nt], 0, 0, 0);
        }
    }
#pragma unroll
    for (int kk = 0; kk < 4; ++kk) {
        const int kb = kk * 32 + kq;
        bf16x8 a = (bf16x8)0;
        if (valid) a = *(const bf16x8*)(xin + (size_t)mrow * 128 + kb);
#pragma unroll
        for (int nt = 0; nt < 8; ++nt) {
            const bf16x8 b = *(const bf16x8*)(Wr + (size_t)(nt * 16 + (lane & 15)) * 128 + kb);
            acc[nt] = __builtin_amdgcn_mfma_f32_16x16x32_bf16(a, b, acc[nt], 0, 0, 0);
        }
    }

    const int col0  = lane & 15;
    const int rbase = m0 + (lane >> 4) * 4;
#pragma unroll
    for (int nt = 0; nt < 8; ++nt) {
        const int col = nt * 16 + col0;
        const float bc = bias[col];
#pragma unroll
        for (int r = 0; r < 4; ++r) {
            const int node = rbase + r;
            if (node < N) {
                float v = acc[nt][r] + bc;
                if (RELU) outb[(size_t)node * 128 + col] = f2bf(fmaxf(v, 0.0f));
                else      outf[(size_t)node * 128 + col] = v;
            }
        }
    }
}

extern "C" void kernel_launch(void* const* d_in, const int* in_sizes, int n_in,
                              void* d_out, int out_size, void* d_ws, size_t ws_size,
                              hipStream_t stream) {
    const float* x   = (const float*)d_in[0];
    const int*   ei  = (const int*)d_in[1];
    const float* Wl1 = (const float*)d_in[2];
    const float* bl1 = (const float*)d_in[3];
    const float* Wr1 = (const float*)d_in[4];
    const float* Wl2 = (const float*)d_in[5];
    const float* bl2 = (const float*)d_in[6];
    const float* Wr2 = (const float*)d_in[7];

    const int N = in_sizes[0] / 128;
    const int E = in_sizes[1] / 2;
    const int* src = ei;
    const int* dst = ei + E;
    const int B = (N + NPB - 1) >> BSHIFT;   // 196 for N=100000

    // ws: h_bf16 | mean_bf16 | 4x bf16 weights | rowptr | csr | binned | meta
    char* wsb = (char*)d_ws;
    short* hbuf = (short*)wsb;                                  // N*128 bf16
    size_t off = (size_t)N * 128 * 2;
    short* mean = (short*)(wsb + off); off += (size_t)N * 128 * 2;
    short* wl1 = (short*)(wsb + off); off += 16384 * 2;
    short* wr1 = (short*)(wsb + off); off += 16384 * 2;
    short* wl2 = (short*)(wsb + off); off += 16384 * 2;
    short* wr2 = (short*)(wsb + off); off += 16384 * 2;
    int* rowptr = (int*)(wsb + off);                            // N+1
    off += ((size_t)(N + 1) * 4 + 15) & ~(size_t)15;
    int* csr = (int*)(wsb + off);                               // E
    off += ((size_t)E * 4 + 15) & ~(size_t)15;
    unsigned int* binned = (unsigned int*)(wsb + off);          // E
    off += ((size_t)E * 4 + 15) & ~(size_t)15;
    int* bcnt  = (int*)(wsb + off);                             // MAXBUCK+1
    int* bbase = bcnt + (MAXBUCK + 1);                          // MAXBUCK+1
    int* gcur  = bbase + (MAXBUCK + 1);                         // MAXBUCK

    // d_out: xb (bf16 x) at base — read by agg1/gemm1; overwritten by gemm2 last
    short* xb  = (short*)d_out;
    float* out = (float*)d_out;

    const int aggBlocks  = (N + 3) / 4;
    const int gemmBlocks = (N + 63) / 64;
    const int binBlocks  = (E + 4095) / 4096;

    convx_kernel<<<(N * 128 / 8 + 255) / 256, 256, 0, stream>>>(x, xb, N * 128);
    convw4_kernel<<<64, 256, 0, stream>>>(Wl1, Wr1, Wl2, Wr2, wl1, wr1, wl2, wr2);

    // build CSR by destination (bucketed, coalesced)
    (void)hipMemsetAsync(bcnt, 0, (size_t)(MAXBUCK + 1) * sizeof(int), stream);
    bhist_kernel<<<256, 256, 0, stream>>>(dst, bcnt, E, B);
    bscan_kernel<<<1, 256, 0, stream>>>(bcnt, bbase, gcur, rowptr, E, N, B);
    bin_kernel<<<binBlocks, 256, 0, stream>>>(src, dst, gcur, binned, E, B);
    build_kernel<<<B, 256, 0, stream>>>(binned, bbase, rowptr, csr, N);

    // layer 1
    agg_kernel<<<aggBlocks, 256, 0, stream>>>(xb, csr, rowptr, mean, N);
    gemm_kernel<true><<<gemmBlocks, 256, 0, stream>>>(mean, xb, wl1, wr1, bl1,
                                                      hbuf, (float*)nullptr, N);
    // layer 2
    agg_kernel<<<aggBlocks, 256, 0, stream>>>(hbuf, csr, rowptr, mean, N);
    gemm_kernel<false><<<gemmBlocks, 256, 0, stream>>>(mean, hbuf, wl2, wr2, bl2,
                                                       (short*)nullptr, out, N);
}